// Round 4
// baseline (176.488 us; speedup 1.0000x reference)
//
#include <hip/hip_runtime.h>

// 5-layer MLP: [B,64] -> 32 -> 12 -> 8 -> 6 -> 2, ReLU between, fp32.
// 2 rows per thread; layer-0 software-pipelined in 8-float chunks
// (double-buffered, dependence-forced overlap); packed-fp32 accumulators
// (v_pk_fma_f32) with weights streamed as uniform 8B scalar loads.

typedef float v2f __attribute__((ext_vector_type(2)));

#define BLOCK 256
#define RPT 2

template <int IN, int OUT, bool RELU>
__device__ __forceinline__ void vlayer(const float* __restrict__ W,
                                       const float* __restrict__ b,
                                       const v2f* hin, v2f* hout) {
#pragma unroll
    for (int o = 0; o < OUT / 2; ++o)
        hout[o] = *reinterpret_cast<const v2f*>(&b[2 * o]);
#pragma unroll
    for (int i = 0; i < IN; ++i) {
        const float v = hin[i >> 1][i & 1];
        const v2f xv = {v, v};
#pragma unroll
        for (int o = 0; o < OUT / 2; ++o) {
            const v2f w = *reinterpret_cast<const v2f*>(&W[i * OUT + 2 * o]);
            hout[o] = __builtin_elementwise_fma(w, xv, hout[o]);
        }
    }
    if (RELU) {
#pragma unroll
        for (int o = 0; o < OUT / 2; ++o) {
            hout[o][0] = fmaxf(hout[o][0], 0.0f);
            hout[o][1] = fmaxf(hout[o][1], 0.0f);
        }
    }
}

__global__ __launch_bounds__(BLOCK) void mlp_kernel(
        const float* __restrict__ x,
        const float* __restrict__ W0, const float* __restrict__ b0,
        const float* __restrict__ W1, const float* __restrict__ b1,
        const float* __restrict__ W2, const float* __restrict__ b2,
        const float* __restrict__ W3, const float* __restrict__ b3,
        const float* __restrict__ W4, const float* __restrict__ b4,
        float* __restrict__ out, int nrows) {
    const int t = threadIdx.x;
    const long long rbase = (long long)blockIdx.x * (BLOCK * RPT) + t;

    const float4* p0 = reinterpret_cast<const float4*>(x + rbase * 64);
    const float4* p1 = reinterpret_cast<const float4*>(x + (rbase + BLOCK) * 64);

    // Double-buffered 8-float chunks, 2 rows. Slot A = even chunks, B = odd.
    float4 A0[2], A1[2], B0[2], B1[2];
    A0[0] = p0[0]; A0[1] = p0[1]; A1[0] = p1[0]; A1[1] = p1[1];
    B0[0] = p0[2]; B0[1] = p0[3]; B1[0] = p1[2]; B1[1] = p1[3];

    v2f acc0[16], acc1[16];
#pragma unroll
    for (int o = 0; o < 16; ++o) {
        const v2f bb = *reinterpret_cast<const v2f*>(&b0[2 * o]);
        acc0[o] = bb;
        acc1[o] = bb;
    }

#pragma unroll
    for (int c = 0; c < 8; ++c) {
        float xs0[8], xs1[8];
        if ((c & 1) == 0) {
            xs0[0] = A0[0].x; xs0[1] = A0[0].y; xs0[2] = A0[0].z; xs0[3] = A0[0].w;
            xs0[4] = A0[1].x; xs0[5] = A0[1].y; xs0[6] = A0[1].z; xs0[7] = A0[1].w;
            xs1[0] = A1[0].x; xs1[1] = A1[0].y; xs1[2] = A1[0].z; xs1[3] = A1[0].w;
            xs1[4] = A1[1].x; xs1[5] = A1[1].y; xs1[6] = A1[1].z; xs1[7] = A1[1].w;
            if (c + 2 < 8) {  // refill slot A with chunk c+2
                A0[0] = p0[2 * (c + 2)];     A0[1] = p0[2 * (c + 2) + 1];
                A1[0] = p1[2 * (c + 2)];     A1[1] = p1[2 * (c + 2) + 1];
            }
        } else {
            xs0[0] = B0[0].x; xs0[1] = B0[0].y; xs0[2] = B0[0].z; xs0[3] = B0[0].w;
            xs0[4] = B0[1].x; xs0[5] = B0[1].y; xs0[6] = B0[1].z; xs0[7] = B0[1].w;
            xs1[0] = B1[0].x; xs1[1] = B1[0].y; xs1[2] = B1[0].z; xs1[3] = B1[0].w;
            xs1[4] = B1[1].x; xs1[5] = B1[1].y; xs1[6] = B1[1].z; xs1[7] = B1[1].w;
            if (c + 2 < 8) {  // refill slot B with chunk c+2
                B0[0] = p0[2 * (c + 2)];     B0[1] = p0[2 * (c + 2) + 1];
                B1[0] = p1[2 * (c + 2)];     B1[1] = p1[2 * (c + 2) + 1];
            }
        }
#pragma unroll
        for (int k = 0; k < 8; ++k) {
            const v2f xv0 = {xs0[k], xs0[k]};
            const v2f xv1 = {xs1[k], xs1[k]};
#pragma unroll
            for (int o = 0; o < 16; ++o) {
                const v2f w =
                    *reinterpret_cast<const v2f*>(&W0[(8 * c + k) * 32 + 2 * o]);
                acc0[o] = __builtin_elementwise_fma(w, xv0, acc0[o]);
                acc1[o] = __builtin_elementwise_fma(w, xv1, acc1[o]);
            }
        }
    }

    // ReLU on h0
#pragma unroll
    for (int o = 0; o < 16; ++o) {
        acc0[o][0] = fmaxf(acc0[o][0], 0.0f);
        acc0[o][1] = fmaxf(acc0[o][1], 0.0f);
        acc1[o][0] = fmaxf(acc1[o][0], 0.0f);
        acc1[o][1] = fmaxf(acc1[o][1], 0.0f);
    }

    v2f h1a[6], h1b[6], h2a[4], h2b[4], h3a[3], h3b[3], h4a[1], h4b[1];
    vlayer<32, 12, true>(W1, b1, acc0, h1a);
    vlayer<32, 12, true>(W1, b1, acc1, h1b);
    vlayer<12, 8, true>(W2, b2, h1a, h2a);
    vlayer<12, 8, true>(W2, b2, h1b, h2b);
    vlayer<8, 6, true>(W3, b3, h2a, h3a);
    vlayer<8, 6, true>(W3, b3, h2b, h3b);
    vlayer<6, 2, false>(W4, b4, h3a, h4a);
    vlayer<6, 2, false>(W4, b4, h3b, h4b);

    float2* outv = reinterpret_cast<float2*>(out);
    outv[rbase] = make_float2(h4a[0][0], h4a[0][1]);
    outv[rbase + BLOCK] = make_float2(h4b[0][0], h4b[0][1]);
}

extern "C" void kernel_launch(void* const* d_in, const int* in_sizes, int n_in,
                              void* d_out, int out_size, void* d_ws, size_t ws_size,
                              hipStream_t stream) {
    const float* x  = (const float*)d_in[0];
    const float* W0 = (const float*)d_in[1];
    const float* b0 = (const float*)d_in[2];
    const float* W1 = (const float*)d_in[3];
    const float* b1 = (const float*)d_in[4];
    const float* W2 = (const float*)d_in[5];
    const float* b2 = (const float*)d_in[6];
    const float* W3 = (const float*)d_in[7];
    const float* b3 = (const float*)d_in[8];
    const float* W4 = (const float*)d_in[9];
    const float* b4 = (const float*)d_in[10];
    float* out = (float*)d_out;

    const int nrows = in_sizes[0] / 64;                  // 1048576
    const int grid = (nrows + BLOCK * RPT - 1) / (BLOCK * RPT);  // 2048
    mlp_kernel<<<grid, BLOCK, 0, stream>>>(x, W0, b0, W1, b1, W2, b2,
                                           W3, b3, W4, b4, out, nrows);
}